// Round 4
// baseline (702.751 us; speedup 1.0000x reference)
//
#include <hip/hip_runtime.h>
#include <math.h>

#define HID 512
#define TLEN 4096
#define BATCH 64

// ---------------------------------------------------------------------------
// K1: v[b,h] = sum_o hidden[b,o] * W[o,h]    (v = hidden @ W, [B,H])
// Bias term dot(b, hidden[b]) is softmax-invariant and dropped deliberately.
// One block per b, 512 threads (one per h). ~10 us, not the bottleneck.
// ---------------------------------------------------------------------------
__global__ __launch_bounds__(HID) void proj_kernel(const float* __restrict__ hidden,
                                                   const float* __restrict__ W,
                                                   float* __restrict__ v) {
    __shared__ float hs[HID];
    const int b = blockIdx.x;
    const int h = threadIdx.x;
    hs[h] = hidden[b * HID + h];
    __syncthreads();
    float s = 0.f;
#pragma unroll 16
    for (int o = 0; o < HID; ++o) {
        s = fmaf(hs[o], W[o * HID + h], s);
    }
    v[b * HID + h] = s;
}

// ---------------------------------------------------------------------------
// K2: scores[b,t] = dot(enc[b,t,:], v[b,:])
// RESTRUCTURED: 8 lanes per row. Wave = 8 groups x 8 lanes; group g owns row
// t, lane j reads float4 (k*8 + j) so each group-load is one fully-used
// 128 B line (8 lines per wave instruction, perfectly coalesced). All 16
// chunk loads per row are independent -> deep MLP. v staged in LDS (2 KB),
// read as broadcast float4 (conflict-free). Cross-lane reduction: only
// 3 shfl_xor per 8 rows (vs 6 per row before) — 16x fewer LDS-pipe ops/byte.
// Wave covers 32 rows (4 batches of 8); block of 4 waves = 128 rows;
// grid (32, 64) = 2048 blocks = exactly 8 blocks/CU resident.
// ---------------------------------------------------------------------------
__global__ __launch_bounds__(256) void score_kernel(const float* __restrict__ enc,
                                                    const float* __restrict__ v,
                                                    float* __restrict__ scores) {
    __shared__ float4 vs[HID / 4];   // 2 KB
    const int b    = blockIdx.y;
    const int tid  = threadIdx.x;
    const int wave = tid >> 6;
    const int lane = tid & 63;
    const int g    = lane >> 3;      // group 0..7 (one row each)
    const int j    = lane & 7;       // lane within group

    if (tid < HID / 4) vs[tid] = ((const float4*)(v + b * HID))[tid];
    __syncthreads();

    const float4* e4 = (const float4*)(enc + (size_t)b * TLEN * HID);
    const int rowBase = blockIdx.x * 128 + wave * 32;

#pragma unroll
    for (int batch = 0; batch < 4; ++batch) {
        const int t = rowBase + batch * 8 + g;
        const float4* row = e4 + (size_t)t * (HID / 4);
        float s0 = 0.f, s1 = 0.f;
#pragma unroll
        for (int k = 0; k < 16; k += 2) {
            const float4 a0 = row[k * 8 + j];
            const float4 a1 = row[(k + 1) * 8 + j];
            const float4 v0 = vs[k * 8 + j];
            const float4 v1 = vs[(k + 1) * 8 + j];
            s0 += a0.x * v0.x + a0.y * v0.y + a0.z * v0.z + a0.w * v0.w;
            s1 += a1.x * v1.x + a1.y * v1.y + a1.z * v1.z + a1.w * v1.w;
        }
        float s = s0 + s1;
        s += __shfl_xor(s, 1, 64);
        s += __shfl_xor(s, 2, 64);
        s += __shfl_xor(s, 4, 64);
        if (j == 0) scores[b * TLEN + t] = s;   // 8 consecutive dwords per wave
    }
}

// ---------------------------------------------------------------------------
// K3: out[b,0,t] = softmax_t(scores[b,:])   one 1024-thread block per b,
// 4 elements/thread via float4. Two block reductions (max, sum). Unchanged.
// ---------------------------------------------------------------------------
__global__ __launch_bounds__(1024) void softmax_kernel(const float* __restrict__ scores,
                                                       float* __restrict__ out) {
    __shared__ float redm[16];
    __shared__ float reds[16];
    const int b    = blockIdx.x;
    const int tid  = threadIdx.x;
    const int wave = tid >> 6;
    const int lane = tid & 63;

    const float4 x = ((const float4*)(scores + b * TLEN))[tid];

    // --- block max ---
    float m = fmaxf(fmaxf(x.x, x.y), fmaxf(x.z, x.w));
#pragma unroll
    for (int off = 32; off; off >>= 1) m = fmaxf(m, __shfl_xor(m, off, 64));
    if (lane == 0) redm[wave] = m;
    __syncthreads();
    if (wave == 0) {
        float t = (lane < 16) ? redm[lane] : -INFINITY;
#pragma unroll
        for (int off = 8; off; off >>= 1) t = fmaxf(t, __shfl_xor(t, off, 64));
        if (lane == 0) redm[0] = t;
    }
    __syncthreads();
    m = redm[0];

    // --- exp + block sum ---
    float4 e;
    e.x = __expf(x.x - m);
    e.y = __expf(x.y - m);
    e.z = __expf(x.z - m);
    e.w = __expf(x.w - m);
    float sum = e.x + e.y + e.z + e.w;
#pragma unroll
    for (int off = 32; off; off >>= 1) sum += __shfl_xor(sum, off, 64);
    if (lane == 0) reds[wave] = sum;
    __syncthreads();
    if (wave == 0) {
        float t = (lane < 16) ? reds[lane] : 0.f;
#pragma unroll
        for (int off = 8; off; off >>= 1) t += __shfl_xor(t, off, 64);
        if (lane == 0) reds[0] = t;
    }
    __syncthreads();
    const float inv = 1.0f / reds[0];

    float4 o4;
    o4.x = e.x * inv; o4.y = e.y * inv; o4.z = e.z * inv; o4.w = e.w * inv;
    ((float4*)(out + b * TLEN))[tid] = o4;
}

extern "C" void kernel_launch(void* const* d_in, const int* in_sizes, int n_in,
                              void* d_out, int out_size, void* d_ws, size_t ws_size,
                              hipStream_t stream) {
    const float* hidden = (const float*)d_in[0];   // [B, H]
    const float* enc    = (const float*)d_in[1];   // [B, T, H]
    const float* W      = (const float*)d_in[2];   // [H, H]
    // d_in[3] = bias — intentionally unused (cancels under softmax)
    float* out = (float*)d_out;                    // [B, 1, T]

    // workspace layout: v [B*H] floats, then scores [B*T] floats (16B aligned)
    float* v      = (float*)d_ws;
    float* scores = v + BATCH * HID;

    proj_kernel<<<dim3(BATCH), dim3(HID), 0, stream>>>(hidden, W, v);
    score_kernel<<<dim3(TLEN / 128, BATCH), dim3(256), 0, stream>>>(enc, v, scores);
    softmax_kernel<<<dim3(BATCH), dim3(1024), 0, stream>>>(scores, out);
}

// Round 5
// 699.801 us; speedup vs baseline: 1.0042x; 1.0042x over previous
//
#include <hip/hip_runtime.h>
#include <math.h>

#define HID 512
#define TLEN 4096
#define BATCH 64

#define TILE_ROWS 16
#define ROWS_PER_BLOCK 512
#define TILES_PER_BLOCK (ROWS_PER_BLOCK / TILE_ROWS)   // 32
#define TILE_F4 (TILE_ROWS * HID / 4)                  // 2048 float4 = 32 KB

#define GLOBAL_AS __attribute__((address_space(1)))
#define LDS_AS    __attribute__((address_space(3)))

// ---------------------------------------------------------------------------
// K1: v[b,h] = sum_o hidden[b,o] * W[o,h]    (v = hidden @ W, [B,H])
// Bias dot(b,hidden) is softmax-invariant, dropped. ~10 us, not bottleneck.
// ---------------------------------------------------------------------------
__global__ __launch_bounds__(HID) void proj_kernel(const float* __restrict__ hidden,
                                                   const float* __restrict__ W,
                                                   float* __restrict__ v) {
    __shared__ float hs[HID];
    const int b = blockIdx.x;
    const int h = threadIdx.x;
    hs[h] = hidden[b * HID + h];
    __syncthreads();
    float s = 0.f;
#pragma unroll 16
    for (int o = 0; o < HID; ++o) {
        s = fmaf(hs[o], W[o * HID + h], s);
    }
    v[b * HID + h] = s;
}

// ---------------------------------------------------------------------------
// K2: scores[b,t] = dot(enc[b,t,:], v[b,:])
// Little's-law fix: both prior versions staged enc through VGPRs, capping
// in-flight bytes at ~2 KB/CU (need ~9.3 KB at 900-cyc latency) -> ~1.5 TB/s.
// Now: double-buffered direct-to-LDS streaming via global_load_lds width=16
// (zero VGPR cost per outstanding load; up to 32 KB in flight per block,
// 2 blocks/CU). Compute reads tiles from LDS; v LDS-resident.
//   - block = 4 waves, handles 512 rows of one batch as 32 tiles x 16 rows
//   - stage(T+1) issued before compute(T); __syncthreads drains vmcnt;
//     the drain bubble of one block is covered by its sibling block.
//   - wave = 4 groups x 16 lanes; group g owns row w*4+g; lane j reads
//     LDS float4 slot k*16+j (linear layout == global linear, verified).
//   - reduction: 4 shfl_xor per 16 rows. Stores: 4 consecutive dwords/wave.
// LDS: 64 KB buf + 2 KB v = 66 KB -> exactly 2 blocks/CU. Grid 512 = 2/CU.
// ---------------------------------------------------------------------------
__global__ __launch_bounds__(256) void score_kernel(const float* __restrict__ enc,
                                                    const float* __restrict__ v,
                                                    float* __restrict__ scores) {
    __shared__ float4 vs[HID / 4];          // 2 KB
    __shared__ float4 buf[2][TILE_F4];      // 64 KB (2 x 32 KB tiles)

    const int b    = blockIdx.y;
    const int bx   = blockIdx.x;
    const int tid  = threadIdx.x;
    const int w    = tid >> 6;      // wave 0..3
    const int lane = tid & 63;
    const int g    = lane >> 4;     // group 0..3 (one row each)
    const int j    = lane & 15;     // lane within group

    if (tid < HID / 4) vs[tid] = ((const float4*)(v + b * HID))[tid];

    // tile-contiguous global base: rows [bx*512, bx*512+512) of batch b
    const float4* encT = (const float4*)enc
                       + ((size_t)b * TLEN + (size_t)bx * ROWS_PER_BLOCK) * (HID / 4);

    // stage tile T into buf[T&1]: per wave, 8 x global_load_lds of 1 KB.
    // LDS dest is wave-uniform; HW adds lane*16. Global src is per-lane.
    // LDS float4 (w*512 + i*64 + lane)  <-  global float4 (T*2048 + same).
    auto stage = [&](int T) {
        const float4* gsrc = encT + (size_t)T * TILE_F4 + w * 512 + lane;
        float4* ldst = &buf[T & 1][w * 512];
#pragma unroll
        for (int i = 0; i < 8; ++i) {
            __builtin_amdgcn_global_load_lds(
                (GLOBAL_AS const void*)(gsrc + i * 64),
                (LDS_AS void*)(ldst + i * 64),
                16, 0, 0);
        }
    };

    stage(0);
    __syncthreads();   // vmcnt(0) drain: tile 0 resident, vs resident

    for (int T = 0; T < TILES_PER_BLOCK; ++T) {
        if (T + 1 < TILES_PER_BLOCK) stage(T + 1);   // overlaps compute(T)

        const float4* src = &buf[T & 1][(w * 4 + g) * (HID / 4)];
        float acc = 0.f;
#pragma unroll
        for (int k = 0; k < 8; ++k) {
            const float4 e  = src[k * 16 + j];
            const float4 vv = vs[k * 16 + j];
            acc += e.x * vv.x + e.y * vv.y + e.z * vv.z + e.w * vv.w;
        }
        acc += __shfl_xor(acc, 1, 64);
        acc += __shfl_xor(acc, 2, 64);
        acc += __shfl_xor(acc, 4, 64);
        acc += __shfl_xor(acc, 8, 64);
        if (j == 0)
            scores[b * TLEN + bx * ROWS_PER_BLOCK + T * TILE_ROWS + w * 4 + g] = acc;

        __syncthreads();   // drains stage(T+1); protects buf[T&1] before reuse
    }
}

// ---------------------------------------------------------------------------
// K3: out[b,0,t] = softmax_t(scores[b,:])   one 1024-thread block per b,
// 4 elements/thread via float4. Two block reductions (max, sum). Unchanged.
// ---------------------------------------------------------------------------
__global__ __launch_bounds__(1024) void softmax_kernel(const float* __restrict__ scores,
                                                       float* __restrict__ out) {
    __shared__ float redm[16];
    __shared__ float reds[16];
    const int b    = blockIdx.x;
    const int tid  = threadIdx.x;
    const int wave = tid >> 6;
    const int lane = tid & 63;

    const float4 x = ((const float4*)(scores + b * TLEN))[tid];

    // --- block max ---
    float m = fmaxf(fmaxf(x.x, x.y), fmaxf(x.z, x.w));
#pragma unroll
    for (int off = 32; off; off >>= 1) m = fmaxf(m, __shfl_xor(m, off, 64));
    if (lane == 0) redm[wave] = m;
    __syncthreads();
    if (wave == 0) {
        float t = (lane < 16) ? redm[lane] : -INFINITY;
#pragma unroll
        for (int off = 8; off; off >>= 1) t = fmaxf(t, __shfl_xor(t, off, 64));
        if (lane == 0) redm[0] = t;
    }
    __syncthreads();
    m = redm[0];

    // --- exp + block sum ---
    float4 e;
    e.x = __expf(x.x - m);
    e.y = __expf(x.y - m);
    e.z = __expf(x.z - m);
    e.w = __expf(x.w - m);
    float sum = e.x + e.y + e.z + e.w;
#pragma unroll
    for (int off = 32; off; off >>= 1) sum += __shfl_xor(sum, off, 64);
    if (lane == 0) reds[wave] = sum;
    __syncthreads();
    if (wave == 0) {
        float t = (lane < 16) ? reds[lane] : 0.f;
#pragma unroll
        for (int off = 8; off; off >>= 1) t += __shfl_xor(t, off, 64);
        if (lane == 0) reds[0] = t;
    }
    __syncthreads();
    const float inv = 1.0f / reds[0];

    float4 o4;
    o4.x = e.x * inv; o4.y = e.y * inv; o4.z = e.z * inv; o4.w = e.w * inv;
    ((float4*)(out + b * TLEN))[tid] = o4;
}

extern "C" void kernel_launch(void* const* d_in, const int* in_sizes, int n_in,
                              void* d_out, int out_size, void* d_ws, size_t ws_size,
                              hipStream_t stream) {
    const float* hidden = (const float*)d_in[0];   // [B, H]
    const float* enc    = (const float*)d_in[1];   // [B, T, H]
    const float* W      = (const float*)d_in[2];   // [H, H]
    // d_in[3] = bias — intentionally unused (cancels under softmax)
    float* out = (float*)d_out;                    // [B, 1, T]

    // workspace layout: v [B*H] floats, then scores [B*T] floats (16B aligned)
    float* v      = (float*)d_ws;
    float* scores = v + BATCH * HID;

    proj_kernel<<<dim3(BATCH), dim3(HID), 0, stream>>>(hidden, W, v);
    score_kernel<<<dim3(TLEN / ROWS_PER_BLOCK, BATCH), dim3(256), 0, stream>>>(enc, v, scores);
    softmax_kernel<<<dim3(BATCH), dim3(1024), 0, stream>>>(scores, out);
}